// Round 3
// baseline (102.063 us; speedup 1.0000x reference)
//
#include <hip/hip_runtime.h>
#include <math.h>

// PhysQuadModel rollout, fully parallel over (env, time).
// Closed-form quaternion power + 6-scalar prefix scan (see round-2 derivation).
// Round-3 changes: HW v_sin/v_cos for per-row trig, polynomial half-atan2 on
// the unit circle (no divide), pre-rotated Rodrigues basis (R(q0) hoisted).

namespace {
constexpr float DT_  = 0.01f;
constexpr float G_   = 9.81f;
constexpr float TTW_ = 1.8f;
constexpr float M_   = 0.033f;
constexpr float KT_  = 3.72e-08f;
constexpr float EPS_ = 1e-6f;
constexpr float INV2PI = 0.15915494309189535f;
constexpr float PI_F   = 3.14159265358979f;
constexpr float PIH_F  = 1.57079632679490f;
}

__device__ __forceinline__ void fsincos(float x, float& s, float& c) {
#if __has_builtin(__builtin_amdgcn_sinf) && __has_builtin(__builtin_amdgcn_cosf)
    float r = x * INV2PI;
    r = r - floorf(r);              // v_fract; v_sin/v_cos take revolutions
    s = __builtin_amdgcn_sinf(r);
    c = __builtin_amdgcn_cosf(r);
#else
    s = sinf(x); c = cosf(x);
#endif
}

// atan2(nv, qw) for nv >= 0 with nv^2 + qw^2 == 1 (unit circle).
// asin-poly on [0, 0.7072] + quadrant selects; no division. abs err ~3e-5.
__device__ __forceinline__ float half_atan2_unit(float nv, float qw) {
    float aw = fabsf(qw);
    float m  = fminf(nv, aw);
    float t  = m * m;
    float p  = 0.01155185f;
    p = fmaf(p, t, 0.01396482f);
    p = fmaf(p, t, 0.01735277f);
    p = fmaf(p, t, 0.02237216f);
    p = fmaf(p, t, 0.03038194f);
    p = fmaf(p, t, 0.04464286f);
    p = fmaf(p, t, 0.075f);
    p = fmaf(p, t, 0.16666667f);
    p = fmaf(p, t, 1.0f);
    p = p * m;                                  // asin(m)
    float h = (nv < aw) ? ((qw >= 0.0f) ? p : (PI_F - p))
                        : (PIH_F - copysignf(p, qw));
    return h;
}

__device__ __forceinline__ float4 qmul(float4 p, float4 q) {
    return make_float4(
        p.w*q.x + q.w*p.x + (p.y*q.z - p.z*q.y),
        p.w*q.y + q.w*p.y + (p.z*q.x - p.x*q.z),
        p.w*q.z + q.w*p.z + (p.x*q.y - p.y*q.x),
        p.w*q.w - (p.x*q.x + p.y*q.y + p.z*q.z));
}

__device__ __forceinline__ float4 qnormalize(float4 q) {
    float inv = 1.0f / sqrtf(q.x*q.x + q.y*q.y + q.z*q.z + q.w*q.w);
    return make_float4(q.x*inv, q.y*inv, q.z*inv, q.w*inv);
}

__device__ __forceinline__ float4 qmul_pure(float4 n, float wx, float wy, float wz) {
    return make_float4(
        n.w*wx + (n.y*wz - n.z*wy),
        n.w*wy + (n.z*wx - n.x*wz),
        n.w*wz + (n.x*wy - n.y*wx),
        -(n.x*wx + n.y*wy + n.z*wz));
}

__global__ __launch_bounds__(256)
void quad_scan_kernel(const float* __restrict__ x0,
                      const float4* __restrict__ u_seq,
                      float* __restrict__ out,
                      int B, int N)
{
    const int wave = threadIdx.x >> 6;
    const int lane = threadIdx.x & 63;
    const int env  = blockIdx.x * 4 + wave;
    if (env >= B) return;

    const float4* xs4 = (const float4*)(x0 + (size_t)env * 12);
    float4 xA = xs4[0], xB = xs4[1], xC = xs4[2];
    const float px0 = xA.x, py0 = xA.y, pz0 = xA.z;
    const float vx0 = xA.w, vy0 = xB.x, vz0 = xB.y;
    const float rx  = xB.z, ry  = xB.w, rz  = xC.x;
    const float ox  = xC.y, oy  = xC.z, oz  = xC.w;

    // ---- q0 from axis-angle (library trig: once per env, feeds everything) ----
    float ang = sqrtf(rx*rx + ry*ry + rz*rz);
    float hf  = 0.5f * ang;
    float sh, ch;
    sincosf(hf, &sh, &ch);
    float so = (ang < EPS_) ? (0.5f - ang*ang*(1.0f/48.0f)) : (sh / ang);
    float4 q0 = make_float4(rx*so, ry*so, rz*so, ch);

    // ---- fixed RK4 stage quats (right factors), per env ----
    const float dt = DT_, dt4 = 0.25f*dt, dt2 = 0.5f*dt, dt12 = dt*(1.0f/12.0f);
    float4 n2 = qnormalize(make_float4(dt4*ox, dt4*oy, dt4*oz, 1.0f));
    float4 m2 = qmul_pure(n2, ox, oy, oz);
    float4 n3 = qnormalize(make_float4(dt4*m2.x, dt4*m2.y, dt4*m2.z, 1.0f + dt4*m2.w));
    float4 m3 = qmul_pure(n3, ox, oy, oz);
    float4 n4 = qnormalize(make_float4(dt2*m3.x, dt2*m3.y, dt2*m3.z, 1.0f + dt2*m3.w));
    float4 m4 = qmul_pure(n4, ox, oy, oz);
    float4 P  = qnormalize(make_float4(
        dt12*(ox + 2.0f*m2.x + 2.0f*m3.x + m4.x),
        dt12*(oy + 2.0f*m2.y + 2.0f*m3.y + m4.y),
        dt12*(oz + 2.0f*m2.z + 2.0f*m3.z + m4.z),
        1.0f + dt12*(2.0f*m2.w + 2.0f*m3.w + m4.w)));

    #define COL3X(q) (2.0f*((q).x*(q).z + (q).w*(q).y))
    #define COL3Y(q) (2.0f*((q).y*(q).z - (q).w*(q).x))
    #define COL3Z(q) (1.0f - 2.0f*((q).x*(q).x + (q).y*(q).y))
    float c2x = COL3X(n2), c2y = COL3Y(n2), c2z = COL3Z(n2);
    float c3x = COL3X(n3), c3y = COL3Y(n3), c3z = COL3Z(n3);
    float c4x = COL3X(n4), c4y = COL3Y(n4), c4z = COL3Z(n4);
    float Cvx = 2.0f*(c2x + c3x) + c4x;
    float Cvy = 2.0f*(c2y + c3y) + c4y;
    float Cvz = 1.0f + 2.0f*(c2z + c3z) + c4z;
    float Cpx = c2x + c3x;
    float Cpy = c2y + c3y;
    float Cpz = 1.0f + c2z + c3z;

    // axis / half-angle of P
    float un   = sqrtf(P.x*P.x + P.y*P.y + P.z*P.z);
    float phih = atan2f(un, P.w);     // library: multiplied by t<=256, keep exact
    float theta = 2.0f * phih;
    float ux, uy, uz;
    if (un > 1e-20f) { float iu = 1.0f/un; ux = P.x*iu; uy = P.y*iu; uz = P.z*iu; }
    else             { ux = 0.0f; uy = 0.0f; uz = 1.0f; }

    // Rodrigues decomposition of Cv, Cp about u
    float dv = ux*Cvx + uy*Cvy + uz*Cvz;
    float vpx = dv*ux, vpy = dv*uy, vpz = dv*uz;
    float vex = Cvx - vpx, vey = Cvy - vpy, vez = Cvz - vpz;
    float vcx = uy*Cvz - uz*Cvy, vcy = uz*Cvx - ux*Cvz, vcz = ux*Cvy - uy*Cvx;
    float dp = ux*Cpx + uy*Cpy + uz*Cpz;
    float ppx = dp*ux, ppy = dp*uy, ppz = dp*uz;
    float pex = Cpx - ppx, pey = Cpy - ppy, pez = Cpz - ppz;
    float pcx = uy*Cpz - uz*Cpy, pcy = uz*Cpx - ux*Cpz, pcz = ux*Cpy - uy*Cpx;

    // rotation matrix of q0; pre-rotate all 6 basis vectors (hoists 18 FMA/row)
    float qx = q0.x, qy = q0.y, qz = q0.z, qw = q0.w;
    float r00 = 1.0f - 2.0f*(qy*qy + qz*qz), r01 = 2.0f*(qx*qy - qw*qz), r02 = 2.0f*(qx*qz + qw*qy);
    float r10 = 2.0f*(qx*qy + qw*qz), r11 = 1.0f - 2.0f*(qx*qx + qz*qz), r12 = 2.0f*(qy*qz - qw*qx);
    float r20 = 2.0f*(qx*qz - qw*qy), r21 = 2.0f*(qy*qz + qw*qx), r22 = 1.0f - 2.0f*(qx*qx + qy*qy);
    #define ROT_X(X,Y,Z) (r00*(X) + r01*(Y) + r02*(Z))
    #define ROT_Y(X,Y,Z) (r10*(X) + r11*(Y) + r12*(Z))
    #define ROT_Z(X,Y,Z) (r20*(X) + r21*(Y) + r22*(Z))
    float Gvpx = ROT_X(vpx,vpy,vpz), Gvpy = ROT_Y(vpx,vpy,vpz), Gvpz = ROT_Z(vpx,vpy,vpz);
    float Gvex = ROT_X(vex,vey,vez), Gvey = ROT_Y(vex,vey,vez), Gvez = ROT_Z(vex,vey,vez);
    float Gvcx = ROT_X(vcx,vcy,vcz), Gvcy = ROT_Y(vcx,vcy,vcz), Gvcz = ROT_Z(vcx,vcy,vcz);
    float Gppx = ROT_X(ppx,ppy,ppz), Gppy = ROT_Y(ppx,ppy,ppz), Gppz = ROT_Z(ppx,ppy,ppz);
    float Gpex = ROT_X(pex,pey,pez), Gpey = ROT_Y(pex,pey,pez), Gpez = ROT_Z(pex,pey,pez);
    float Gpcx = ROT_X(pcx,pcy,pcz), Gpcy = ROT_Y(pcx,pcy,pcz), Gpcz = ROT_Z(pcx,pcy,pcz);

    const float T_MAX   = TTW_ * M_ * G_;
    const float invTMAX = 1.0f / T_MAX;
    const float TACC    = TTW_ * G_;

    // ---- per-lane contributions + serial inclusive sums (4 steps/lane) ----
    const float4* __restrict__ up = u_seq + (size_t)env * N;
    float la[4], lb[4], lc[4], lA[4], lB[4], lC[4];
    float sa = 0.f, sb = 0.f, sc = 0.f, sA = 0.f, sB = 0.f, sC = 0.f;
    const int k0 = lane * 4;
    #pragma unroll
    for (int j = 0; j < 4; ++j) {
        int k = k0 + j;
        float Ta = 0.f, cs = 1.f, sn = 0.f, kf = (float)k;
        if (k < N) {
            float4 u = up[k];
            float w2 = u.x*u.x + u.y*u.y + u.z*u.z + u.w*u.w;
            float Tn = fminf(fmaxf(KT_*w2*invTMAX, 0.0f), 1.0f);
            Ta = Tn * TACC;
            fsincos(theta * kf, sn, cs);
        }
        sa += Ta;        sb += Ta*cs;     sc += Ta*sn;
        sA += kf*Ta;     sB += kf*Ta*cs;  sC += kf*Ta*sn;
        la[j] = sa; lb[j] = sb; lc[j] = sc;
        lA[j] = sA; lB[j] = sB; lC[j] = sC;
    }

    // ---- wave-wide inclusive scan of lane totals ----
    float ta = sa, tb = sb, tc = sc, tA = sA, tB = sB, tC = sC;
    #pragma unroll
    for (int d = 1; d < 64; d <<= 1) {
        float xa = __shfl_up(ta, d), xb = __shfl_up(tb, d), xc = __shfl_up(tc, d);
        float xA = __shfl_up(tA, d), xB = __shfl_up(tB, d), xC = __shfl_up(tC, d);
        if (lane >= d) { ta += xa; tb += xb; tc += xc; tA += xA; tB += xB; tC += xC; }
    }
    const float ba = ta - sa, bb = tb - sb, bc = tc - sc;
    const float bA = tA - sA, bB = tB - sB, bC = tC - sC;

    // ---- emit 4 output rows per lane ----
    float* __restrict__ op = out + (size_t)env * N * 12;
    const float dt6  = dt * (1.0f/6.0f);
    const float dt26 = dt * dt * (1.0f/6.0f);
    #pragma unroll
    for (int j = 0; j < 4; ++j) {
        int k = k0 + j;
        if (k >= N) break;
        float Ea = ba + la[j], Eb = bb + lb[j], Ec = bc + lc[j];
        float EA = bA + lA[j], EB = bB + lB[j], EC = bC + lC[j];
        float tf = (float)(k + 1);
        float cw = tf - 1.0f;
        float Wa = cw*Ea - EA, Wb = cw*Eb - EB, Wc = cw*Ec - EC;

        float rvx = Gvpx*Ea + Gvex*Eb + Gvcx*Ec;
        float rvy = Gvpy*Ea + Gvey*Eb + Gvcy*Ec;
        float rvz = Gvpz*Ea + Gvez*Eb + Gvcz*Ec;
        float rpx = Gvpx*Wa + Gvex*Wb + Gvcx*Wc + Gppx*Ea + Gpex*Eb + Gpcx*Ec;
        float rpy = Gvpy*Wa + Gvey*Wb + Gvcy*Wc + Gppy*Ea + Gpey*Eb + Gpcy*Ec;
        float rpz = Gvpz*Wa + Gvez*Wb + Gvcz*Wc + Gppz*Ea + Gpez*Eb + Gpcz*Ec;

        float velx = vx0 + dt6*rvx;
        float vely = vy0 + dt6*rvy;
        float velz = vz0 + dt6*rvz - tf*dt*G_;
        float posx = px0 + tf*dt*vx0 + dt26*rpx;
        float posy = py0 + tf*dt*vy0 + dt26*rpy;
        float posz = pz0 + tf*dt*vz0 + dt26*rpz - 0.5f*tf*tf*dt*dt*G_;

        // q_t = q0 (x) (u sin(t*phih), cos(t*phih))
        float st, ct;
        fsincos(phih * tf, st, ct);
        float4 Pt = make_float4(ux*st, uy*st, uz*st, ct);
        float4 qt = qmul(q0, Pt);

        // quat -> so3: angle = 2*atan2(|qv|, qw) on the unit circle
        float nv  = sqrtf(qt.x*qt.x + qt.y*qt.y + qt.z*qt.z);
        float h   = half_atan2_unit(nv, qt.w);
        float scl = 2.0f * h / fmaxf(nv, 1e-12f);
        float srx = qt.x*scl, sry = qt.y*scl, srz = qt.z*scl;

        float4* o4 = (float4*)(op + (size_t)k * 12);
        o4[0] = make_float4(posx, posy, posz, velx);
        o4[1] = make_float4(vely, velz, srx, sry);
        o4[2] = make_float4(srz, ox, oy, oz);
    }
}

extern "C" void kernel_launch(void* const* d_in, const int* in_sizes, int n_in,
                              void* d_out, int out_size, void* d_ws, size_t ws_size,
                              hipStream_t stream) {
    const float*  x0    = (const float*)d_in[0];
    const float4* u_seq = (const float4*)d_in[1];
    float* out = (float*)d_out;
    int B = in_sizes[0] / 12;
    int N = in_sizes[1] / (B * 4);
    dim3 grid((B + 3) / 4), block(256);
    hipLaunchKernelGGL(quad_scan_kernel, grid, block, 0, stream,
                       x0, u_seq, out, B, N);
}